// Round 1
// baseline (1193.874 us; speedup 1.0000x reference)
//
#include <hip/hip_runtime.h>
#include <math.h>

#define LN2F 0.69314718055994531f

typedef _Float16 v8hf __attribute__((ext_vector_type(8)));
typedef float    v4f  __attribute__((ext_vector_type(4)));

__device__ __forceinline__ float ssp_f(float x) {
    // shifted softplus: log(1+exp(x)) - log(2), stable form
    return fmaxf(x, 0.f) + log1pf(expf(-fabsf(x))) - LN2F;
}

// ---------------------------------------------------------------------------
// Y = act(X @ W^T + bias); X: M x 128 (f32), W: 128 x 128 row-major (f32).
// Block: 256 threads, 64 rows. Per-thread 4x8 register tile, LDS-staged
// transposed W and X so the k-loop uses b128 LDS reads (1.5 B/FMA).
// ---------------------------------------------------------------------------
template<bool SSP>
__global__ __launch_bounds__(256)
void lin128_kernel(const float* __restrict__ X, const float* __restrict__ W,
                   const float* __restrict__ bias, float* __restrict__ Y, int M)
{
    __shared__ __align__(16) float Wl[128 * 128]; // [k][j]
    __shared__ __align__(16) float Xt[128 * 68];  // [k][m_local], padded stride
    const int tid = threadIdx.x;
    const int m_base = blockIdx.x * 64;

    for (int idx = tid; idx < 128 * 128; idx += 256) {
        int j = idx >> 7, k = idx & 127;
        Wl[k * 128 + j] = W[idx];
    }
    for (int idx = tid; idx < 64 * 128; idx += 256) {
        int r = idx >> 7, k = idx & 127;
        int m = m_base + r;
        Xt[k * 68 + r] = (m < M) ? X[(size_t)m * 128 + k] : 0.f;
    }
    __syncthreads();

    const int jg = tid & 15;  // 16 col groups of 8
    const int mg = tid >> 4;  // 16 row groups of 4
    const int j0 = jg * 8, r0 = mg * 4;

    float acc[4][8];
    #pragma unroll
    for (int r = 0; r < 4; ++r)
        #pragma unroll
        for (int c = 0; c < 8; ++c) acc[r][c] = 0.f;

    #pragma unroll 4
    for (int k = 0; k < 128; ++k) {
        const float4 xv = *(const float4*)&Xt[k * 68 + r0];
        const float4 wa = *(const float4*)&Wl[k * 128 + j0];
        const float4 wb = *(const float4*)&Wl[k * 128 + j0 + 4];
        const float xr[4] = {xv.x, xv.y, xv.z, xv.w};
        const float wc[8] = {wa.x, wa.y, wa.z, wa.w, wb.x, wb.y, wb.z, wb.w};
        #pragma unroll
        for (int r = 0; r < 4; ++r)
            #pragma unroll
            for (int c = 0; c < 8; ++c)
                acc[r][c] = fmaf(xr[r], wc[c], acc[r][c]);
    }

    float bv[8];
    #pragma unroll
    for (int c = 0; c < 8; ++c) bv[c] = bias ? bias[j0 + c] : 0.f;

    #pragma unroll
    for (int r = 0; r < 4; ++r) {
        int m = m_base + r0 + r;
        if (m < M) {
            float o[8];
            #pragma unroll
            for (int c = 0; c < 8; ++c) {
                float v = acc[r][c] + bv[c];
                o[c] = SSP ? ssp_f(v) : v;
            }
            float4* yp = (float4*)&Y[(size_t)m * 128 + j0];
            yp[0] = make_float4(o[0], o[1], o[2], o[3]);
            yp[1] = make_float4(o[4], o[5], o[6], o[7]);
        }
    }
}

// ---------------------------------------------------------------------------
// Fused edge kernel: per 128-edge tile,
//   t = attr @ W1^T + b1   (f16 MFMA, K padded 50->64)
//   u = ssp(t)             (f32, stored f16 to LDS in A-operand-friendly layout)
//   Wf = u @ W2^T + b2     (f16 MFMA, K=128)
//   msg = Wf * C(edge_weight) * h[src] ; atomicAdd into agg[dst]
// Block: 512 threads = 8 waves; wave w owns edges [w*16, w*16+16).
// MFMA 16x16x32 layouts (guide-verified): A[m=lane&15][k=quad*8+i],
// B[n=lane&15][k=quad*8+i], D row=quad*4+reg, col=lane&15.
// LDS rows padded to 72/136 f16 (16B-aligned strides, conflict-light).
// ---------------------------------------------------------------------------
__global__ __launch_bounds__(512)
void edge_kernel(const float* __restrict__ attr,  // E x 50
                 const float* __restrict__ ew,    // E
                 const int* __restrict__ srcI,
                 const int* __restrict__ dstI,
                 const float* __restrict__ w1,    // 128 x 50
                 const float* __restrict__ b1,    // 128
                 const float* __restrict__ w2,    // 128 x 128
                 const float* __restrict__ b2,    // 128
                 const float* __restrict__ h,     // N x 128
                 float* __restrict__ agg,         // N x 128 (pre-zeroed)
                 int E)
{
    __shared__ __align__(16) _Float16 W2h[128 * 136]; // [j][k]
    __shared__ __align__(16) _Float16 W1h[128 * 72];  // [j][g], g padded to 64
    __shared__ __align__(16) _Float16 Ah [128 * 72];  // [e][g]
    __shared__ __align__(16) _Float16 Uh [128 * 136]; // [e][k]
    __shared__ float b1S[128], b2S[128], Cs[128];
    __shared__ int   sS[128], dS[128];

    const int tid = threadIdx.x;
    const int e_base = blockIdx.x * 128;

    for (int idx = tid; idx < 128 * 64; idx += 512) {
        int j = idx >> 6, g = idx & 63;
        W1h[j * 72 + g] = (g < 50) ? (_Float16)w1[j * 50 + g] : (_Float16)0.f;
    }
    for (int idx = tid; idx < 128 * 128; idx += 512) {
        int j = idx >> 7, k = idx & 127;
        W2h[j * 136 + k] = (_Float16)w2[idx];
    }
    for (int idx = tid; idx < 128 * 64; idx += 512) {
        int r = idx >> 6, g = idx & 63;
        int e = e_base + r;
        float v = (g < 50 && e < E) ? attr[(size_t)e * 50 + g] : 0.f;
        Ah[r * 72 + g] = (_Float16)v;
    }
    if (tid < 128) {
        b1S[tid] = b1[tid];
        b2S[tid] = b2[tid];
        int e = e_base + tid;
        if (e < E) {
            Cs[tid] = 0.5f * (cosf(ew[e] * 0.31415926535897932f) + 1.f);
            sS[tid] = srcI[e];
            dS[tid] = dstI[e];
        } else { Cs[tid] = 0.f; sS[tid] = 0; dS[tid] = 0; }
    }
    __syncthreads();

    const int lane = tid & 63;
    const int wv   = tid >> 6;   // wave 0..7
    const int m0   = wv * 16;    // this wave's edge sub-tile
    const int l15  = lane & 15;
    const int quad = lane >> 4;  // 0..3

    // ---- stage 1 ----
    {
        const v8hf a0 = *(const v8hf*)&Ah[(m0 + l15) * 72 + quad * 8];
        const v8hf a1 = *(const v8hf*)&Ah[(m0 + l15) * 72 + 32 + quad * 8];
        #pragma unroll
        for (int nt = 0; nt < 8; ++nt) {
            const int j0 = nt * 16;
            v4f acc = {0.f, 0.f, 0.f, 0.f};
            const v8hf bA = *(const v8hf*)&W1h[(j0 + l15) * 72 + quad * 8];
            const v8hf bB = *(const v8hf*)&W1h[(j0 + l15) * 72 + 32 + quad * 8];
            acc = __builtin_amdgcn_mfma_f32_16x16x32_f16(a0, bA, acc, 0, 0, 0);
            acc = __builtin_amdgcn_mfma_f32_16x16x32_f16(a1, bB, acc, 0, 0, 0);
            const float bj = b1S[j0 + l15];
            #pragma unroll
            for (int r = 0; r < 4; ++r) {
                float u = ssp_f(acc[r] + bj);
                // D-layout (row=m local, col=j) -> Uh[e][k=j]
                Uh[(m0 + quad * 4 + r) * 136 + j0 + l15] = (_Float16)u;
            }
        }
    }
    __syncthreads();

    // ---- stage 2 + epilogue ----
    v8hf ua[4];
    #pragma unroll
    for (int ks = 0; ks < 4; ++ks)
        ua[ks] = *(const v8hf*)&Uh[(m0 + l15) * 136 + ks * 32 + quad * 8];

    float cC[4]; int cSrc[4], cDst[4]; bool valid[4];
    #pragma unroll
    for (int r = 0; r < 4; ++r) {
        int el = m0 + quad * 4 + r;
        cC[r] = Cs[el]; cSrc[r] = sS[el]; cDst[r] = dS[el];
        valid[r] = (e_base + el) < E;
    }

    #pragma unroll
    for (int nt = 0; nt < 8; ++nt) {
        const int j0 = nt * 16;
        v4f acc = {0.f, 0.f, 0.f, 0.f};
        #pragma unroll
        for (int ks = 0; ks < 4; ++ks) {
            const v8hf b = *(const v8hf*)&W2h[(j0 + l15) * 136 + ks * 32 + quad * 8];
            acc = __builtin_amdgcn_mfma_f32_16x16x32_f16(ua[ks], b, acc, 0, 0, 0);
        }
        const float bj = b2S[j0 + l15];
        const int col = j0 + l15;
        #pragma unroll
        for (int r = 0; r < 4; ++r) {
            if (valid[r]) {
                float wf = (acc[r] + bj) * cC[r];
                float hv = h[(size_t)cSrc[r] * 128 + col];
                atomicAdd(&agg[(size_t)cDst[r] * 128 + col], wf * hv);
            }
        }
    }
}

extern "C" void kernel_launch(void* const* d_in, const int* in_sizes, int n_in,
                              void* d_out, int out_size, void* d_ws, size_t ws_size,
                              hipStream_t stream)
{
    const float* x   = (const float*)d_in[0];
    const int*   ei  = (const int*)  d_in[1];
    const float* ew  = (const float*)d_in[2];
    const float* ea  = (const float*)d_in[3];
    const float* w1  = (const float*)d_in[4];
    const float* b1  = (const float*)d_in[5];
    const float* w2  = (const float*)d_in[6];
    const float* b2  = (const float*)d_in[7];
    const float* l1w = (const float*)d_in[8];
    const float* l2w = (const float*)d_in[9];
    const float* l2b = (const float*)d_in[10];
    const float* lw  = (const float*)d_in[11];
    const float* lb  = (const float*)d_in[12];

    const int N = in_sizes[0] / 128;   // 40000
    const int E = in_sizes[2];         // 640000

    float* hbuf = (float*)d_ws;                  // N*128 f32 (h, later s)
    float* agg  = hbuf + (size_t)N * 128;        // N*128 f32

    const int nb = (N + 63) / 64;

    // h = x @ lin1_w^T (no bias)
    lin128_kernel<false><<<nb, 256, 0, stream>>>(x, l1w, nullptr, hbuf, N);
    // zero the scatter accumulator (ws is poisoned 0xAA before every launch)
    hipMemsetAsync(agg, 0, (size_t)N * 128 * sizeof(float), stream);
    // fused filter-MLP + envelope + gather + scatter-add
    edge_kernel<<<(E + 127) / 128, 512, 0, stream>>>(ea, ew, ei, ei + E,
                                                     w1, b1, w2, b2, hbuf, agg, E);
    // s = ssp(agg @ lin2_w^T + lin2_b)   (reuses hbuf)
    lin128_kernel<true><<<nb, 256, 0, stream>>>(agg, l2w, l2b, hbuf, N);
    // out = s @ lin_w^T + lin_b
    lin128_kernel<false><<<nb, 256, 0, stream>>>(hbuf, lw, lb, (float*)d_out, N);
}